// Round 17
// baseline (4129.239 us; speedup 1.0000x reference)
//
#include <hip/hip_runtime.h>
#include <stdint.h>

namespace {

constexpr int B_   = 512;
constexpr int T_   = 512;
constexpr int IN_  = 6;
constexpr int H_   = 64;
constexpr int HH_  = 128;
constexpr int OUT_ = 8;
constexpr int ME   = 16;          // batch elements per block (MFMA M)
constexpr int PPR  = 390;         // pp row stride (pad: 4*390 % 128B != 0 -> banks spread)

typedef _Float16 f16x8 __attribute__((ext_vector_type(8)));
typedef float    f32x4 __attribute__((ext_vector_type(4)));

__device__ __forceinline__ f32x4 mfma16(f16x8 a, f16x8 b, f32x4 c) {
    return __builtin_amdgcn_mfma_f32_16x16x32_f16(a, b, c, 0, 0, 0);
}

// B-fragment: lane supplies B[k0 + (lane>>4)*8 + s][n0 + (lane&15)], s=0..7
__device__ __forceinline__ f16x8 loadB(const float* __restrict__ W, int N,
                                       int k0, int n0, int lane) {
    f16x8 r;
    const int kb = k0 + ((lane >> 4) << 3);
    const int n  = n0 + (lane & 15);
    #pragma unroll
    for (int s = 0; s < 8; ++s) r[s] = (_Float16)W[(kb + s) * N + n];
    return r;
}

// A-fragment from LDS act buffer: layout chunk = k>>3, u32[chunk*64 + m*4 .. +3]
// lane reads A[m=lane&15][k = ks + (lane>>4)*8 + s] -> one b128, linear across lanes.
__device__ __forceinline__ f16x8 loadA(const uint32_t* __restrict__ buf, int ks, int lane) {
    uint4 q = *reinterpret_cast<const uint4*>(
        buf + (((ks >> 3) + (lane >> 4)) << 6) + ((lane & 15) << 2));
    return __builtin_bit_cast(f16x8, q);
}

__device__ __forceinline__ float tanh_fast(float v) {
    float ax = fabsf(v);
    float e  = __expf(2.0f * ax);
    float r  = 1.0f - 2.0f / (e + 1.0f);
    return copysignf(r, v);
}

// One workgroup (512 threads, 8 waves) per 16 batch elements; grid 32.
// All GEMVs become M=16 MFMA GEMMs (mfma_f32_16x16x32_f16).
// Wave w owns n-tile w for G1/G2/G3 and n-tiles {3w,3w+1,3w+2} for G4.
// B-fragments: b1[2]+b2[4]+b4[12] in regs (72 u32); G3's b3[4] in
// lane-interleaved LDS (zero-conflict). Activations ping-pong bufA/bufB
// (fragment-linear layout). einsum/RK4 scalar via pp (pad-390).
__global__ __launch_bounds__(512, 2) void cde_kernel(
    const float* __restrict__ x,
    const float* __restrict__ W_init, const float* __restrict__ b_init,
    const float* __restrict__ W_in,   const float* __restrict__ b_in,
    const float* __restrict__ W_h1,   const float* __restrict__ b_h1,
    const float* __restrict__ W_h2,   const float* __restrict__ b_h2,
    const float* __restrict__ W_out,  const float* __restrict__ b_out,
    const float* __restrict__ W_fin,  const float* __restrict__ b_fin,
    float* __restrict__ out)
{
    const int t    = threadIdx.x;
    const int lane = t & 63;
    const int w    = t >> 6;               // wave 0..7
    const int b0   = blockIdx.x * ME;

    __shared__ alignas(16) uint32_t bufA[16 * 64];      // act ping (h / z2), 4KB
    __shared__ alignas(16) uint32_t bufB[16 * 64];      // act pong (z1 / z3), 4KB
    __shared__ alignas(16) uint32_t b3s[4 * 512 * 4];   // G3 B-frags, lane-interleaved, 32KB
    __shared__ float pp[ME * PPR];                      // tanh(A)*dx products
    __shared__ float hbuf[ME * 68];                     // h f32, padded rows
    __shared__ float dxs[ME * IN_];
    __shared__ float wfin_s[H_ * 9];
    __shared__ float bfin_s[OUT_];

    // ---- B-fragments ----
    f16x8 b1[2], b2[4], b4[12];
    #pragma unroll
    for (int ks = 0; ks < 2; ++ks) b1[ks] = loadB(W_in, HH_, ks * 32, w * 16, lane);
    #pragma unroll
    for (int ks = 0; ks < 4; ++ks) b2[ks] = loadB(W_h1, HH_, ks * 32, w * 16, lane);
    #pragma unroll
    for (int ks = 0; ks < 4; ++ks) {
        f16x8 v = loadB(W_h2, HH_, ks * 32, w * 16, lane);
        *reinterpret_cast<uint4*>(&b3s[(ks * 512 + t) * 4]) = __builtin_bit_cast(uint4, v);
    }
    #pragma unroll
    for (int tt = 0; tt < 3; ++tt)
        #pragma unroll
        for (int ks = 0; ks < 4; ++ks)
            b4[tt * 4 + ks] = loadB(W_out, 384, ks * 32, w * 48 + tt * 16, lane);

    const float binw = b_in[w * 16 + (lane & 15)];
    const float bh1w = b_h1[w * 16 + (lane & 15)];
    const float bh2w = b_h2[w * 16 + (lane & 15)];
    float bow[3];
    int   imod[3];
    #pragma unroll
    for (int tt = 0; tt < 3; ++tt) {
        int n = w * 48 + tt * 16 + (lane & 15);
        bow[tt]  = b_out[n];
        imod[tt] = n % 6;
    }
    for (int i = t; i < H_ * OUT_; i += 512) wfin_s[(i >> 3) * 9 + (i & 7)] = W_fin[i];
    if (t < OUT_) bfin_s[t] = b_fin[t];

    // dX producers: threads 0..95 (e = t/6, i = t%6)
    float  xa = 0.f, xb = 0.f;
    size_t xdbase = 0;
    if (t < 96) {
        int e = t / 6, i = t - 6 * (t / 6);
        xdbase = ((size_t)(b0 + e) * T_) * IN_ + i;
        xa = x[xdbase];
        xb = x[xdbase + IN_];
        dxs[t] = xb - xa;                  // dX for step 0
        xa = xb;
        xb = x[xdbase + 2 * IN_];
    }

    // ---- h0: each thread owns pairs (e0, r0) and (e0+8, r0) ----
    const int e0 = t >> 6;        // 0..7
    const int r0 = t & 63;
    float h_reg[2], hacc[2] = {0.f, 0.f};
    #pragma unroll
    for (int pq = 0; pq < 2; ++pq) {
        int e = e0 + pq * 8;
        const float* xe = x + (size_t)(b0 + e) * T_ * IN_;
        float s = b_init[r0];
        #pragma unroll
        for (int i = 0; i < IN_; ++i) s += xe[i] * W_init[i * H_ + r0];
        h_reg[pq] = s;
        hbuf[e * 68 + r0] = s;
        ((_Float16*)bufA)[(r0 >> 3) * 128 + e * 8 + (r0 & 7)] = (_Float16)s;
    }
    __syncthreads();

#define OUT_STAGE(TT)                                                          \
    if (t < 128) {                                                             \
        int e_ = t >> 3, o_ = t & 7;                                           \
        float s_ = bfin_s[o_];                                                 \
        _Pragma("unroll 8")                                                    \
        for (int r_ = 0; r_ < 64; ++r_)                                        \
            s_ += hbuf[e_ * 68 + r_] * wfin_s[r_ * 9 + o_];                    \
        out[(size_t)(b0 + e_) * T_ * OUT_ + (size_t)(TT) * OUT_ + o_] = s_;    \
    }

    OUT_STAGE(0)

    for (int step = 0; step < T_ - 1; ++step) {
        #pragma unroll
        for (int s4 = 0; s4 < 4; ++s4) {
            // ---- phase 1: G1 h(64) -> z1 into bufB (+ OUT on s4==0) ----
            if (s4 == 0 && step > 0) { OUT_STAGE(step) }
            {
                f32x4 acc = {0.f, 0.f, 0.f, 0.f};
                acc = mfma16(loadA(bufA, 0, lane),  b1[0], acc);
                acc = mfma16(loadA(bufA, 32, lane), b1[1], acc);
                int n  = w * 16 + (lane & 15);
                int bi = (n >> 3) * 128 + (n & 7) + ((lane >> 4) * 4) * 8;
                _Float16* zb = (_Float16*)bufB;
                #pragma unroll
                for (int j = 0; j < 4; ++j)
                    zb[bi + j * 8] = (_Float16)fmaxf(acc[j] + binw, 0.f);
            }
            __syncthreads();

            // ---- phase 2: G2 z1 -> z2 into bufA ----
            {
                f32x4 acc = {0.f, 0.f, 0.f, 0.f};
                #pragma unroll
                for (int ks = 0; ks < 4; ++ks)
                    acc = mfma16(loadA(bufB, ks * 32, lane), b2[ks], acc);
                int n  = w * 16 + (lane & 15);
                int bi = (n >> 3) * 128 + (n & 7) + ((lane >> 4) * 4) * 8;
                _Float16* zb = (_Float16*)bufA;
                #pragma unroll
                for (int j = 0; j < 4; ++j)
                    zb[bi + j * 8] = (_Float16)fmaxf(acc[j] + bh1w, 0.f);
            }
            __syncthreads();

            // ---- phase 3: G3 z2 -> z3 into bufB (B-frags from LDS) ----
            {
                f32x4 acc = {0.f, 0.f, 0.f, 0.f};
                #pragma unroll
                for (int ks = 0; ks < 4; ++ks) {
                    f16x8 bb = __builtin_bit_cast(f16x8,
                        *reinterpret_cast<const uint4*>(&b3s[(ks * 512 + t) * 4]));
                    acc = mfma16(loadA(bufA, ks * 32, lane), bb, acc);
                }
                int n  = w * 16 + (lane & 15);
                int bi = (n >> 3) * 128 + (n & 7) + ((lane >> 4) * 4) * 8;
                _Float16* zb = (_Float16*)bufB;
                #pragma unroll
                for (int j = 0; j < 4; ++j)
                    zb[bi + j * 8] = (_Float16)fmaxf(acc[j] + bh2w, 0.f);
            }
            __syncthreads();

            // ---- phase 4: G4 z3 -> A (3 n-tiles), tanh, *dX -> pp ----
            {
                f32x4 a0 = {0.f, 0.f, 0.f, 0.f};
                f32x4 a1 = {0.f, 0.f, 0.f, 0.f};
                f32x4 a2 = {0.f, 0.f, 0.f, 0.f};
                #pragma unroll
                for (int ks = 0; ks < 4; ++ks) {
                    f16x8 av = loadA(bufB, ks * 32, lane);
                    a0 = mfma16(av, b4[ks],     a0);
                    a1 = mfma16(av, b4[4 + ks], a1);
                    a2 = mfma16(av, b4[8 + ks], a2);
                }
                const int mb = (lane >> 4) * 4;
                #pragma unroll
                for (int tt = 0; tt < 3; ++tt) {
                    int n = w * 48 + tt * 16 + (lane & 15);
                    const f32x4& ac = (tt == 0) ? a0 : ((tt == 1) ? a1 : a2);
                    #pragma unroll
                    for (int j = 0; j < 4; ++j) {
                        int m = mb + j;
                        pp[m * PPR + n] = tanh_fast(ac[j] + bow[tt]) * dxs[m * 6 + imod[tt]];
                    }
                }
            }
            __syncthreads();

            // ---- phase 5: kv + RK4 + next-h into bufA (+ dX update) ----
            {
                #pragma unroll
                for (int pq = 0; pq < 2; ++pq) {
                    int e = e0 + pq * 8;
                    const float* pr = &pp[e * PPR + r0 * 6];
                    float kv = (pr[0] + pr[1]) + (pr[2] + pr[3]) + (pr[4] + pr[5]);
                    hacc[pq] += ((s4 == 1 || s4 == 2) ? 2.0f : 1.0f) * kv;
                    float hs;
                    if (s4 < 3) {
                        hs = h_reg[pq] + ((s4 == 2) ? 1.0f : 0.5f) * kv;
                    } else {
                        h_reg[pq] += hacc[pq] * (1.0f / 6.0f);
                        hacc[pq] = 0.f;
                        hs = h_reg[pq];
                        hbuf[e * 68 + r0] = h_reg[pq];
                    }
                    ((_Float16*)bufA)[(r0 >> 3) * 128 + e * 8 + (r0 & 7)] = (_Float16)hs;
                }
                if (s4 == 3 && step + 2 < T_ && t < 96) {
                    dxs[t] = xb - xa;
                    xa = xb;
                    if (step + 3 < T_) xb = x[xdbase + (size_t)(step + 3) * IN_];
                }
            }
            __syncthreads();
        }
    }

    OUT_STAGE(T_ - 1)
#undef OUT_STAGE
}

} // namespace

extern "C" void kernel_launch(void* const* d_in, const int* in_sizes, int n_in,
                              void* d_out, int out_size, void* d_ws, size_t ws_size,
                              hipStream_t stream) {
    const float* x      = (const float*)d_in[0];
    const float* W_init = (const float*)d_in[1];
    const float* b_init = (const float*)d_in[2];
    const float* W_in   = (const float*)d_in[3];
    const float* b_in   = (const float*)d_in[4];
    const float* W_h1   = (const float*)d_in[5];
    const float* b_h1   = (const float*)d_in[6];
    const float* W_h2   = (const float*)d_in[7];
    const float* b_h2   = (const float*)d_in[8];
    const float* W_out  = (const float*)d_in[9];
    const float* b_out  = (const float*)d_in[10];
    const float* W_fin  = (const float*)d_in[11];
    const float* b_fin  = (const float*)d_in[12];
    float* out = (float*)d_out;

    cde_kernel<<<dim3(B_ / ME), dim3(512), 0, stream>>>(
        x, W_init, b_init, W_in, b_in, W_h1, b_h1, W_h2, b_h2,
        W_out, b_out, W_fin, b_fin, out);
}

// Round 18
// 3818.880 us; speedup vs baseline: 1.0813x; 1.0813x over previous
//
#include <hip/hip_runtime.h>
#include <stdint.h>

namespace {

constexpr int B_   = 512;
constexpr int T_   = 512;
constexpr int IN_  = 6;
constexpr int H_   = 64;
constexpr int HH_  = 128;
constexpr int OUT_ = 8;
constexpr int ME   = 16;          // batch elements per block (MFMA M)

typedef _Float16 f16x8 __attribute__((ext_vector_type(8)));
typedef float    f32x4 __attribute__((ext_vector_type(4)));

__device__ __forceinline__ f32x4 mfma16(f16x8 a, f16x8 b, f32x4 c) {
    return __builtin_amdgcn_mfma_f32_16x16x32_f16(a, b, c, 0, 0, 0);
}

// B-fragment: lane supplies B[k0 + (lane>>4)*8 + s][n0 + (lane&15)], s=0..7
// (layout verified end-to-end by R17: absmax 7.8e-3 with real weights)
__device__ __forceinline__ f16x8 loadB(const float* __restrict__ W, int N,
                                       int k0, int n0, int lane) {
    f16x8 r;
    const int kb = k0 + ((lane >> 4) << 3);
    const int n  = n0 + (lane & 15);
    #pragma unroll
    for (int s = 0; s < 8; ++s) r[s] = (_Float16)W[(kb + s) * N + n];
    return r;
}

// A-fragment from LDS act buffer (chunk = k>>3; u32[chunk*64 + m*4 .. +3])
__device__ __forceinline__ f16x8 loadA(const uint32_t* __restrict__ buf, int ks, int lane) {
    uint4 q = *reinterpret_cast<const uint4*>(
        buf + (((ks >> 3) + (lane >> 4)) << 6) + ((lane & 15) << 2));
    return __builtin_bit_cast(f16x8, q);
}

__device__ __forceinline__ uint32_t packh2(float a, float b) {
    union { _Float16 h[2]; uint32_t u; } p;
    p.h[0] = (_Float16)a;
    p.h[1] = (_Float16)b;
    return p.u;
}

__device__ __forceinline__ float tanh_fast(float v) {
    float ax = fabsf(v);
    float e  = __expf(2.0f * ax);
    float r  = 1.0f - 2.0f / (e + 1.0f);
    return copysignf(r, v);
}

// One workgroup (512 threads, 8 waves) per 16 batch elements; grid 32.
// 4 barrier-phases per vf eval: {G1+OUT} {G2} {G3} {G4+einsum+RK4+h}.
// The merge works because wave w's G4 cols 48w..48w+48 = h-rows 8w..8w+8
// exactly, so einsum/RK4/h-write are wave-local (private ppw scratch, no
// barrier). OUT = 2 MFMAs on wave 0. dxs double-buffered by step parity.
__global__ __launch_bounds__(512, 2) void cde_kernel(
    const float* __restrict__ x,
    const float* __restrict__ W_init, const float* __restrict__ b_init,
    const float* __restrict__ W_in,   const float* __restrict__ b_in,
    const float* __restrict__ W_h1,   const float* __restrict__ b_h1,
    const float* __restrict__ W_h2,   const float* __restrict__ b_h2,
    const float* __restrict__ W_out,  const float* __restrict__ b_out,
    const float* __restrict__ W_fin,  const float* __restrict__ b_fin,
    float* __restrict__ out)
{
    const int t    = threadIdx.x;
    const int lane = t & 63;
    const int w    = t >> 6;               // wave 0..7
    const int le   = lane & 15;            // element slot in fragments
    const int lq2  = lane >> 4;            // 0..3 (row-group)
    const int b0   = blockIdx.x * ME;

    __shared__ alignas(16) uint32_t bufA[16 * 64];      // h / z2, 4KB
    __shared__ alignas(16) uint32_t bufB[16 * 64];      // z1 / z3, 4KB
    __shared__ alignas(16) uint32_t b3s[4 * 512 * 4];   // G3 B-frags, 32KB
    __shared__ float ppw[8][16 * 49];                   // per-wave einsum scratch
    __shared__ float dxs[2][ME * IN_];                  // step-parity dbuf

    // ---- B-fragments: b1[2]+b2[4]+b4[12] regs (72 u32); b3 in LDS ----
    f16x8 b1[2], b2[4], b4[12];
    #pragma unroll
    for (int ks = 0; ks < 2; ++ks) b1[ks] = loadB(W_in, HH_, ks * 32, w * 16, lane);
    #pragma unroll
    for (int ks = 0; ks < 4; ++ks) b2[ks] = loadB(W_h1, HH_, ks * 32, w * 16, lane);
    #pragma unroll
    for (int ks = 0; ks < 4; ++ks) {
        f16x8 v = loadB(W_h2, HH_, ks * 32, w * 16, lane);
        *reinterpret_cast<uint4*>(&b3s[(ks * 512 + t) * 4]) = __builtin_bit_cast(uint4, v);
    }
    #pragma unroll
    for (int tt = 0; tt < 3; ++tt)
        #pragma unroll
        for (int ks = 0; ks < 4; ++ks)
            b4[tt * 4 + ks] = loadB(W_out, 384, ks * 32, w * 48 + tt * 16, lane);

    const float binw = b_in[w * 16 + le];
    const float bh1w = b_h1[w * 16 + le];
    const float bh2w = b_h2[w * 16 + le];
    float bow[3];
    int   imod[3];
    #pragma unroll
    for (int tt = 0; tt < 3; ++tt) {
        int n = w * 48 + tt * 16 + le;
        bow[tt]  = b_out[n];
        imod[tt] = n % 6;
    }

    // W_fin B-frags + b_fin (wave 0 only; cols 8..15 zero-padded)
    f16x8 wf0, wf1;
    float bfin_r = 0.f;
    #pragma unroll
    for (int s = 0; s < 8; ++s) { wf0[s] = (_Float16)0.f; wf1[s] = (_Float16)0.f; }
    if (w == 0) {
        #pragma unroll
        for (int s = 0; s < 8; ++s) {
            wf0[s] = (le < 8) ? (_Float16)W_fin[(lq2 * 8 + s) * OUT_ + le] : (_Float16)0.f;
            wf1[s] = (le < 8) ? (_Float16)W_fin[(32 + lq2 * 8 + s) * OUT_ + le] : (_Float16)0.f;
        }
        bfin_r = (le < 8) ? b_fin[le] : 0.f;
    }

    // dX producers: threads 0..95 (e = t/6, i = t%6)
    float  xa = 0.f, xb = 0.f;
    size_t xdb = 0;
    if (t < 96) {
        int e = t / 6, i = t - 6 * (t / 6);
        xdb = ((size_t)(b0 + e) * T_) * IN_ + i;
        xa = x[xdb];
        xb = x[xdb + IN_];
        dxs[0][t] = xb - xa;               // dX for step 0
        xa = xb;
        xb = x[xdb + 2 * IN_];
    }

    // ---- h0: lane owns (e=le, r=8w+2*lq2+p), p=0,1 ----
    float h_reg[2], hacc[2] = {0.f, 0.f};
    {
        const float* xe = x + (size_t)(b0 + le) * T_ * IN_;
        float xr[IN_];
        #pragma unroll
        for (int i = 0; i < IN_; ++i) xr[i] = xe[i];
        #pragma unroll
        for (int p = 0; p < 2; ++p) {
            int r = 8 * w + 2 * lq2 + p;
            float s = b_init[r];
            #pragma unroll
            for (int i = 0; i < IN_; ++i) s += xr[i] * W_init[i * H_ + r];
            h_reg[p] = s;
        }
        *reinterpret_cast<uint32_t*>((_Float16*)bufA + (w * 128 + le * 8 + 2 * lq2)) =
            packh2(h_reg[0], h_reg[1]);
    }
    __syncthreads();

#define OUT_MFMA(TT)                                                           \
    {                                                                          \
        f32x4 oc = {0.f, 0.f, 0.f, 0.f};                                       \
        oc = mfma16(loadA(bufA, 0, lane),  wf0, oc);                           \
        oc = mfma16(loadA(bufA, 32, lane), wf1, oc);                           \
        if (le < 8) {                                                          \
            _Pragma("unroll")                                                  \
            for (int j = 0; j < 4; ++j) {                                      \
                int m = lq2 * 4 + j;                                           \
                out[((size_t)(b0 + m) * T_ + (TT)) * OUT_ + le] = oc[j] + bfin_r; \
            }                                                                  \
        }                                                                      \
    }

    for (int step = 0; step < T_ - 1; ++step) {
        const float* dxc = dxs[step & 1];
        float*       dxn = dxs[(step + 1) & 1];
        #pragma unroll
        for (int s4 = 0; s4 < 4; ++s4) {
            // ---- ph1: G1 h -> z1 into bufB (+ OUT on s4==0, wave 0) ----
            if (s4 == 0 && w == 0) { OUT_MFMA(step) }
            {
                f32x4 acc = {0.f, 0.f, 0.f, 0.f};
                acc = mfma16(loadA(bufA, 0, lane),  b1[0], acc);
                acc = mfma16(loadA(bufA, 32, lane), b1[1], acc);
                int n  = w * 16 + le;
                int bi = (n >> 3) * 128 + (n & 7) + lq2 * 32;
                _Float16* zb = (_Float16*)bufB;
                #pragma unroll
                for (int j = 0; j < 4; ++j)
                    zb[bi + j * 8] = (_Float16)fmaxf(acc[j] + binw, 0.f);
            }
            __syncthreads();

            // ---- ph2: G2 z1 -> z2 into bufA (2 indep acc chains) ----
            {
                f32x4 a0 = {0.f, 0.f, 0.f, 0.f};
                f32x4 a1 = {0.f, 0.f, 0.f, 0.f};
                a0 = mfma16(loadA(bufB, 0, lane),  b2[0], a0);
                a1 = mfma16(loadA(bufB, 32, lane), b2[1], a1);
                a0 = mfma16(loadA(bufB, 64, lane), b2[2], a0);
                a1 = mfma16(loadA(bufB, 96, lane), b2[3], a1);
                int n  = w * 16 + le;
                int bi = (n >> 3) * 128 + (n & 7) + lq2 * 32;
                _Float16* zb = (_Float16*)bufA;
                #pragma unroll
                for (int j = 0; j < 4; ++j)
                    zb[bi + j * 8] = (_Float16)fmaxf(a0[j] + a1[j] + bh1w, 0.f);
            }
            __syncthreads();

            // ---- ph3: G3 z2 -> z3 into bufB (B-frags from LDS) ----
            {
                f32x4 a0 = {0.f, 0.f, 0.f, 0.f};
                f32x4 a1 = {0.f, 0.f, 0.f, 0.f};
                #pragma unroll
                for (int ks = 0; ks < 4; ++ks) {
                    f16x8 bb = __builtin_bit_cast(f16x8,
                        *reinterpret_cast<const uint4*>(&b3s[(ks * 512 + t) * 4]));
                    if (ks & 1) a1 = mfma16(loadA(bufA, ks * 32, lane), bb, a1);
                    else        a0 = mfma16(loadA(bufA, ks * 32, lane), bb, a0);
                }
                int n  = w * 16 + le;
                int bi = (n >> 3) * 128 + (n & 7) + lq2 * 32;
                _Float16* zb = (_Float16*)bufB;
                #pragma unroll
                for (int j = 0; j < 4; ++j)
                    zb[bi + j * 8] = (_Float16)fmaxf(a0[j] + a1[j] + bh2w, 0.f);
            }
            __syncthreads();

            // ---- ph4: G4 + (wave-local) einsum + RK4 + h-write ----
            {
                f32x4 a0 = {0.f, 0.f, 0.f, 0.f};
                f32x4 a1 = {0.f, 0.f, 0.f, 0.f};
                f32x4 a2 = {0.f, 0.f, 0.f, 0.f};
                #pragma unroll
                for (int ks = 0; ks < 4; ++ks) {
                    f16x8 av = loadA(bufB, ks * 32, lane);
                    a0 = mfma16(av, b4[ks],     a0);
                    a1 = mfma16(av, b4[4 + ks], a1);
                    a2 = mfma16(av, b4[8 + ks], a2);
                }
                // tanh * dx -> wave-private pp scratch (rows m = elements)
                float* pw = ppw[w];
                #pragma unroll
                for (int j = 0; j < 4; ++j) {
                    int m = lq2 * 4 + j;
                    pw[m * 49 + 0 * 16 + le] = tanh_fast(a0[j] + bow[0]) * dxc[m * 6 + imod[0]];
                    pw[m * 49 + 1 * 16 + le] = tanh_fast(a1[j] + bow[1]) * dxc[m * 6 + imod[1]];
                    pw[m * 49 + 2 * 16 + le] = tanh_fast(a2[j] + bow[2]) * dxc[m * 6 + imod[2]];
                }
                // wave-local read-back: kv for (e=le, r=8w+2*lq2+p)
                #pragma unroll
                for (int p = 0; p < 2; ++p) {
                    int q = 2 * lq2 + p;
                    const float* pr = &pw[le * 49 + q * 6];
                    float kv = (pr[0] + pr[1]) + (pr[2] + pr[3]) + (pr[4] + pr[5]);
                    hacc[p] += ((s4 == 1 || s4 == 2) ? 2.0f : 1.0f) * kv;
                    if (s4 < 3) {
                        // hs stored via packh2 below using temp in h-slot trick
                        // (compute hs into kv variable to keep regs tight)
                        kv = h_reg[p] + ((s4 == 2) ? 1.0f : 0.5f) * kv;
                    } else {
                        h_reg[p] += hacc[p] * (1.0f / 6.0f);
                        hacc[p] = 0.f;
                        kv = h_reg[p];
                    }
                    // stash hs in hacc-free temp: reuse local
                    if (p == 0) a0[0] = kv; else a0[1] = kv;
                }
                *reinterpret_cast<uint32_t*>((_Float16*)bufA + (w * 128 + le * 8 + 2 * lq2)) =
                    packh2(a0[0], a0[1]);
                // dX for step+1 (parity buffer: no race with this step's readers)
                if (s4 == 3 && t < 96) {
                    dxn[t] = xb - xa;
                    xa = xb;
                    if (step + 3 < T_) xb = x[xdb + (size_t)(step + 3) * IN_];
                }
            }
            __syncthreads();
        }
    }

    if (w == 0) { OUT_MFMA(T_ - 1) }
#undef OUT_MFMA
}

} // namespace

extern "C" void kernel_launch(void* const* d_in, const int* in_sizes, int n_in,
                              void* d_out, int out_size, void* d_ws, size_t ws_size,
                              hipStream_t stream) {
    const float* x      = (const float*)d_in[0];
    const float* W_init = (const float*)d_in[1];
    const float* b_init = (const float*)d_in[2];
    const float* W_in   = (const float*)d_in[3];
    const float* b_in   = (const float*)d_in[4];
    const float* W_h1   = (const float*)d_in[5];
    const float* b_h1   = (const float*)d_in[6];
    const float* W_h2   = (const float*)d_in[7];
    const float* b_h2   = (const float*)d_in[8];
    const float* W_out  = (const float*)d_in[9];
    const float* b_out  = (const float*)d_in[10];
    const float* W_fin  = (const float*)d_in[11];
    const float* b_fin  = (const float*)d_in[12];
    float* out = (float*)d_out;

    cde_kernel<<<dim3(B_ / ME), dim3(512), 0, stream>>>(
        x, W_init, b_init, W_in, b_in, W_h1, b_h1, W_h2, b_h2,
        W_out, b_out, W_fin, b_fin, out);
}